// Round 1
// baseline (11209.492 us; speedup 1.0000x reference)
//
#include <hip/hip_runtime.h>
#include <hip/hip_bf16.h>

typedef short short8 __attribute__((ext_vector_type(8)));
typedef float float4v __attribute__((ext_vector_type(4)));
typedef __hip_bfloat16 b16;

#define T_ 128

__device__ __forceinline__ float sigm(float x) { return 1.0f / (1.0f + __expf(-x)); }

__device__ __forceinline__ void load_lds16(const void* g, void* l) {
  __builtin_amdgcn_global_load_lds((const __attribute__((address_space(1))) void*)g,
                                   (__attribute__((address_space(3))) void*)l, 16, 0, 0);
}

// ---------------------------------------------------------------- gather E rows -> bf16, t-major rows (r = t*128 + b)
__global__ void gather_x(const int* __restrict__ article, const float* __restrict__ E,
                         b16* __restrict__ Xg) {
  int r = blockIdx.x;
  int b = r & 127, t = r >> 7;
  int tok = article[b * T_ + t];
  const float4* src = (const float4*)(E + (size_t)tok * 1024);
  float4 v = src[threadIdx.x];
  b16* dst = Xg + (size_t)r * 1024 + threadIdx.x * 4;
  dst[0] = __float2bfloat16(v.x);
  dst[1] = __float2bfloat16(v.y);
  dst[2] = __float2bfloat16(v.z);
  dst[3] = __float2bfloat16(v.w);
}

// ---------------------------------------------------------------- stack two fp32 [rows_each x k] into bf16 [2*rows_each x k]
__global__ void cvt_cat2(const float* __restrict__ s0, const float* __restrict__ s1,
                         b16* __restrict__ out, int rows_each, int k, int total) {
  for (int idx = blockIdx.x * 256 + threadIdx.x; idx < total; idx += gridDim.x * 256) {
    int row = idx / k, col = idx - row * k;
    float v = (row < rows_each) ? s0[(size_t)row * k + col]
                                : s1[(size_t)(row - rows_each) * k + col];
    out[idx] = __float2bfloat16(v);
  }
}

// ---------------------------------------------------------------- bias0[j] = (bih+bhh) per cell, j in [0,4096)
__global__ void prep_bias(const float* bf1, const float* bf2, const float* bb1,
                          const float* bb2, float* out) {
  int j = blockIdx.x * 256 + threadIdx.x;
  int c = j >> 11, jj = j & 2047;
  out[j] = c ? (bb1[jj] + bb2[jj]) : (bf1[jj] + bf2[jj]);
}

// ---------------------------------------------------------------- pad dW [1074x2148] -> bf16 [1152x2176], db -> dbpad[1152]
__global__ void prep_dw(const float* __restrict__ dW, const float* __restrict__ db,
                        b16* __restrict__ dWpad, float* __restrict__ dbpad) {
  int idx = blockIdx.x * 256 + threadIdx.x;  // grid sized to exactly 1152*2176
  int r = idx / 2176, k = idx - r * 2176;
  float v = (r < 1074 && k < 2148) ? dW[(size_t)r * 2148 + k] : 0.0f;
  dWpad[idx] = __float2bfloat16(v);
  if (idx < 1152) dbpad[idx] = (idx < 1074) ? db[idx] : 0.0f;
}

// ---------------------------------------------------------------- bf16 GEMM: C[MxN] = A[MxK] @ B2[NxK]^T + bias (opt tanh)
// 128x128 tile, BK=64, global_load_lds(16B) staging with XOR chunk swizzle.
__global__ __launch_bounds__(256) void gemm_bt(
    const b16* __restrict__ A, const b16* __restrict__ B2, b16* __restrict__ C,
    const float* __restrict__ bias, int M, int N, int K, int act) {
  __shared__ __align__(16) b16 As[128 * 64];
  __shared__ __align__(16) b16 Bs[128 * 64];
  const int tid = threadIdx.x;
  const int w = tid >> 6, lane = tid & 63;
  const int quad = lane >> 4, lane16 = lane & 15;
  const int m0 = blockIdx.y * 128, n0 = blockIdx.x * 128;
  const int wm = (w >> 1) * 64, wn = (w & 1) * 64;
  float4v acc[4][4] = {};
  for (int kt = 0; kt < K; kt += 64) {
    __syncthreads();
    #pragma unroll
    for (int i = 0; i < 4; ++i) {
      int s = (i * 4 + w) * 64 + lane;
      int rr = s >> 3, ch = s & 7;
      int gch = ch ^ (rr & 7);
      load_lds16(A + (size_t)(m0 + rr) * K + kt + gch * 8, (char*)As + (i * 4 + w) * 1024);
      load_lds16(B2 + (size_t)(n0 + rr) * K + kt + gch * 8, (char*)Bs + (i * 4 + w) * 1024);
    }
    __syncthreads();
    #pragma unroll
    for (int ks = 0; ks < 2; ++ks) {
      short8 af[4], bfr[4];
      #pragma unroll
      for (int a = 0; a < 4; ++a) {
        int rr = wm + a * 16 + lane16;
        int gg = ks * 4 + quad;
        af[a] = *(const short8*)(As + rr * 64 + (gg ^ (rr & 7)) * 8);
      }
      #pragma unroll
      for (int b = 0; b < 4; ++b) {
        int rr = wn + b * 16 + lane16;
        int gg = ks * 4 + quad;
        bfr[b] = *(const short8*)(Bs + rr * 64 + (gg ^ (rr & 7)) * 8);
      }
      #pragma unroll
      for (int a = 0; a < 4; ++a)
        #pragma unroll
        for (int b = 0; b < 4; ++b)
          acc[a][b] = __builtin_amdgcn_mfma_f32_16x16x32_bf16(af[a], bfr[b], acc[a][b], 0, 0, 0);
    }
  }
  #pragma unroll
  for (int a = 0; a < 4; ++a) {
    #pragma unroll
    for (int b = 0; b < 4; ++b) {
      int col = n0 + wn + b * 16 + lane16;
      float bv = bias ? bias[col] : 0.0f;
      #pragma unroll
      for (int rg = 0; rg < 4; ++rg) {
        int row = m0 + wm + a * 16 + quad * 4 + rg;
        float v = acc[a][b][rg] + bv;
        if (act) v = tanhf(v);
        C[(size_t)row * N + col] = __float2bfloat16(v);
      }
    }
  }
}

// ---------------------------------------------------------------- persistent LSTM scan (one layer, 2 cells)
// 256 blocks x 512 thr. Block: cell c, hidden slice hs=p*32, batch slice rb=r*16.
// Gates for step t: Xproj[t] (precomputed, incl. biases) + h(t-1) @ Whh^T.
// h exchange via hseq[t] (unique buffer per step) + per-domain flag counters.
__global__ __launch_bounds__(512) void lstm_scan(
    const b16* __restrict__ Xproj,   // [128*128][4096]
    const b16* __restrict__ Whh,     // [2][2048][512] bf16
    b16* __restrict__ hseq,          // [128*128][1024]
    int* __restrict__ flags) {       // [128][16] counters, stride-16 ints
  __shared__ __align__(16) b16 As[16 * 520];
  __shared__ float gbuf[8][16][16];
  const int tid = threadIdx.x;
  const int bid = blockIdx.x;
  const int p = bid >> 4, d = bid & 15;   // domain d = c*8 + r; co-domain blocks share bid%16
  const int c = d >> 3, r = d & 7;
  const int rb = r * 16, hs = p * 32;
  const int w = tid >> 6, lane = tid & 63;
  const int quad = lane >> 4, lane16 = lane & 15;
  const int gate = w >> 1, half = w & 1;
  const int colbase = gate * 512 + hs + half * 16;

  // resident weight fragments: wave w owns 16 gate-columns, all K=512
  short8 bfrag[16];
  {
    const b16* wp = Whh + ((size_t)(c * 2048 + colbase + lane16)) * 512 + quad * 8;
    #pragma unroll
    for (int ks = 0; ks < 16; ++ks) bfrag[ks] = *(const short8*)(wp + ks * 32);
  }
  const int bloc = tid >> 5, hh = tid & 31;  // update ownership: (batch rb+bloc, hidden hs+hh)
  float cstate = 0.0f;

  for (int t = 0; t < T_; ++t) {
    float4v acc = {0.f, 0.f, 0.f, 0.f};
    if (t > 0) {
      if (tid == 0) {
        while (__hip_atomic_load(&flags[((t - 1) * 16 + d) * 16], __ATOMIC_ACQUIRE,
                                 __HIP_MEMORY_SCOPE_AGENT) < 16)
          __builtin_amdgcn_s_sleep(1);
      }
      __syncthreads();
      {  // stage h(t-1)[rb..rb+16, cell c] -> LDS [16][520]
        const int row = tid >> 5, chunk = tid & 31;
        const uint4* g = (const uint4*)(hseq + ((size_t)(t - 1) * 128 + rb + row) * 1024 + c * 512);
        uint4 v0 = g[chunk * 2];
        uint4 v1 = g[chunk * 2 + 1];
        *(uint4*)(As + row * 520 + chunk * 16) = v0;
        *(uint4*)(As + row * 520 + chunk * 16 + 8) = v1;
      }
      __syncthreads();
      #pragma unroll
      for (int ks = 0; ks < 16; ++ks) {
        short8 af = *(const short8*)(As + lane16 * 520 + ks * 32 + quad * 8);
        acc = __builtin_amdgcn_mfma_f32_16x16x32_bf16(af, bfrag[ks], acc, 0, 0, 0);
      }
    }
    #pragma unroll
    for (int rg = 0; rg < 4; ++rg) gbuf[w][quad * 4 + rg][lane16] = acc[rg];
    __syncthreads();
    {  // cell update
      const size_t xrow = (size_t)t * 128 + rb + bloc;
      float gv[4];
      #pragma unroll
      for (int g4 = 0; g4 < 4; ++g4) {
        float xp = __bfloat162float(Xproj[xrow * 4096 + c * 2048 + g4 * 512 + hs + hh]);
        gv[g4] = gbuf[g4 * 2 + (hh >> 4)][bloc][hh & 15] + xp;
      }
      float ig = sigm(gv[0]), fg = sigm(gv[1]);
      float gg = tanhf(gv[2]), og = sigm(gv[3]);
      cstate = fg * cstate + ig * gg;
      float hv = og * tanhf(cstate);
      hseq[xrow * 1024 + c * 512 + hs + hh] = __float2bfloat16(hv);
    }
    __threadfence();
    __syncthreads();
    if (tid == 0)
      __hip_atomic_fetch_add(&flags[(t * 16 + d) * 16], 1, __ATOMIC_RELEASE,
                             __HIP_MEMORY_SCOPE_AGENT);
  }
}

// ---------------------------------------------------------------- build rep row [target | context | src_e | pad], write target fp32 out
__global__ void build_rep(const int* __restrict__ article, const int* __restrict__ positions,
                          const int* __restrict__ srcs, const float* __restrict__ E,
                          const float* __restrict__ src_emb, const b16* __restrict__ Xg,
                          const b16* __restrict__ h2seq, b16* __restrict__ rep,
                          float* __restrict__ out) {
  int b = blockIdx.x, tid = threadIdx.x;
  int pos = positions[b], sc = srcs[b];
  for (int k = tid; k < 2176; k += 256) {
    b16 v;
    if (k < 1024)      v = Xg[((size_t)pos * 128 + b) * 1024 + k];
    else if (k < 2048) v = h2seq[((size_t)127 * 128 + b) * 1024 + (k - 1024)];
    else if (k < 2148) v = __float2bfloat16(src_emb[sc * 100 + (k - 2048)]);
    else               v = __float2bfloat16(0.0f);
    rep[(size_t)b * 2176 + k] = v;
  }
  int tok = article[b * T_ + pos];
  for (int k = tid; k < 1024; k += 256)
    out[512 + b * 1024 + k] = E[(size_t)tok * 1024 + k];
}

// ---------------------------------------------------------------- logits + probs
__global__ void classifier(const b16* __restrict__ feat, const float* __restrict__ cW,
                           const float* __restrict__ cb, float* __restrict__ out) {
  __shared__ float red[256];
  int tid = threadIdx.x;
  int pairIdx = tid >> 3, jc = tid & 7;
  int bl = pairIdx >> 1, l = pairIdx & 1;
  int b = blockIdx.x * 16 + bl;
  int j0 = jc * 135, j1 = (j0 + 135 < 1074) ? j0 + 135 : 1074;
  float s = 0.f;
  for (int j = j0; j < j1; ++j)
    s += __bfloat162float(feat[(size_t)b * 1152 + j]) * cW[l * 1074 + j];
  red[tid] = s;
  __syncthreads();
  if (jc == 0) {
    float tot = 0.f;
    #pragma unroll
    for (int q = 0; q < 8; ++q) tot += red[pairIdx * 8 + q];
    tot += cb[l];
    out[b * 2 + l] = tot;
    out[256 + b * 2 + l] = 1.0f / (1.0f + __expf(-tot));
  }
}

// ----------------------------------------------------------------
extern "C" void kernel_launch(void* const* d_in, const int* in_sizes, int n_in,
                              void* d_out, int out_size, void* d_ws, size_t ws_size,
                              hipStream_t stream) {
  const int* article = (const int*)d_in[0];
  const int* positions = (const int*)d_in[1];
  const int* srcs = (const int*)d_in[2];
  const float* E = (const float*)d_in[3];
  const float* src_emb = (const float*)d_in[4];
  const float* Wih0f = (const float*)d_in[5];
  const float* Whh0f = (const float*)d_in[6];
  const float* bih0f = (const float*)d_in[7];
  const float* bhh0f = (const float*)d_in[8];
  const float* Wih0b = (const float*)d_in[9];
  const float* Whh0b = (const float*)d_in[10];
  const float* bih0b = (const float*)d_in[11];
  const float* bhh0b = (const float*)d_in[12];
  const float* Wih1f = (const float*)d_in[13];
  const float* Whh1f = (const float*)d_in[14];
  const float* bih1f = (const float*)d_in[15];
  const float* bhh1f = (const float*)d_in[16];
  const float* Wih1b = (const float*)d_in[17];
  const float* Whh1b = (const float*)d_in[18];
  const float* bih1b = (const float*)d_in[19];
  const float* bhh1b = (const float*)d_in[20];
  const float* dW = (const float*)d_in[21];
  const float* db = (const float*)d_in[22];
  const float* cW = (const float*)d_in[23];
  const float* cb = (const float*)d_in[24];

  char* ws = (char*)d_ws;
  size_t off = 0;
  auto carve = [&](size_t bytes) -> void* {
    void* p = ws + off;
    off += (bytes + 255) & ~(size_t)255;
    return p;
  };
  b16* Xg    = (b16*)carve((size_t)16384 * 1024 * 2);
  b16* h1seq = (b16*)carve((size_t)16384 * 1024 * 2);
  b16* h2seq = (b16*)carve((size_t)16384 * 1024 * 2);
  b16* Xproj = (b16*)carve((size_t)16384 * 4096 * 2);  // reused for layer0 and layer1
  b16* W0cat = (b16*)carve((size_t)4096 * 1024 * 2);
  b16* W1cat = (b16*)carve((size_t)4096 * 1024 * 2);
  b16* Whh0  = (b16*)carve((size_t)2 * 2048 * 512 * 2);
  b16* Whh1  = (b16*)carve((size_t)2 * 2048 * 512 * 2);
  b16* dWpad = (b16*)carve((size_t)1152 * 2176 * 2);
  b16* rep   = (b16*)carve((size_t)128 * 2176 * 2);
  b16* feat  = (b16*)carve((size_t)128 * 1152 * 2);
  float* bias0 = (float*)carve(4096 * 4);
  float* bias1 = (float*)carve(4096 * 4);
  float* dbpad = (float*)carve(1152 * 4);
  int* flags1 = (int*)carve(128 * 16 * 16 * 4);
  int* flags2 = (int*)carve(128 * 16 * 16 * 4);
  (void)ws_size; (void)in_sizes; (void)n_in; (void)out_size;

  hipMemsetAsync(flags1, 0, 2 * 128 * 16 * 16 * 4, stream);

  gather_x<<<16384, 256, 0, stream>>>(article, E, Xg);
  cvt_cat2<<<8192, 256, 0, stream>>>(Wih0f, Wih0b, W0cat, 2048, 1024, 4096 * 1024);
  cvt_cat2<<<8192, 256, 0, stream>>>(Wih1f, Wih1b, W1cat, 2048, 1024, 4096 * 1024);
  cvt_cat2<<<8192, 256, 0, stream>>>(Whh0f, Whh0b, Whh0, 2048, 512, 4096 * 512);
  cvt_cat2<<<8192, 256, 0, stream>>>(Whh1f, Whh1b, Whh1, 2048, 512, 4096 * 512);
  prep_bias<<<16, 256, 0, stream>>>(bih0f, bhh0f, bih0b, bhh0b, bias0);
  prep_bias<<<16, 256, 0, stream>>>(bih1f, bhh1f, bih1b, bhh1b, bias1);
  prep_dw<<<9792, 256, 0, stream>>>(dW, db, dWpad, dbpad);

  gemm_bt<<<dim3(32, 128), 256, 0, stream>>>(Xg, W0cat, Xproj, bias0, 16384, 4096, 1024, 0);
  lstm_scan<<<256, 512, 0, stream>>>(Xproj, Whh0, h1seq, flags1);
  gemm_bt<<<dim3(32, 128), 256, 0, stream>>>(h1seq, W1cat, Xproj, bias1, 16384, 4096, 1024, 0);
  lstm_scan<<<256, 512, 0, stream>>>(Xproj, Whh1, h2seq, flags2);

  build_rep<<<128, 256, 0, stream>>>(article, positions, srcs, E, src_emb, Xg, h2seq, rep,
                                     (float*)d_out);
  gemm_bt<<<dim3(9, 1), 256, 0, stream>>>(rep, dWpad, feat, dbpad, 128, 1152, 2176, 1);
  classifier<<<8, 256, 0, stream>>>(feat, cW, cb, (float*)d_out);
}

// Round 2
// 1400.268 us; speedup vs baseline: 8.0052x; 8.0052x over previous
//
#include <hip/hip_runtime.h>
#include <hip/hip_bf16.h>

typedef short short8 __attribute__((ext_vector_type(8)));
typedef float float4v __attribute__((ext_vector_type(4)));
typedef __hip_bfloat16 b16;
typedef unsigned short ushort_t;

#define T_ 128

__device__ __forceinline__ float sigm(float x) { return 1.0f / (1.0f + __expf(-x)); }
__device__ __forceinline__ float blo(unsigned u) { return __uint_as_float(u << 16); }
__device__ __forceinline__ float bhi(unsigned u) { return __uint_as_float(u & 0xffff0000u); }
__device__ __forceinline__ unsigned pack2bf(float a, float b) {
  b16 ha = __float2bfloat16(a), hb = __float2bfloat16(b);
  return (unsigned)*(ushort_t*)&ha | ((unsigned)*(ushort_t*)&hb << 16);
}

__device__ __forceinline__ void load_lds16(const void* g, void* l) {
  __builtin_amdgcn_global_load_lds((const __attribute__((address_space(1))) void*)g,
                                   (__attribute__((address_space(3))) void*)l, 16, 0, 0);
}

// ---------------------------------------------------------------- gather E rows -> bf16, t-major rows (r = t*128 + b)
__global__ void gather_x(const int* __restrict__ article, const float* __restrict__ E,
                         b16* __restrict__ Xg) {
  int r = blockIdx.x;
  int b = r & 127, t = r >> 7;
  int tok = article[b * T_ + t];
  const float4* src = (const float4*)(E + (size_t)tok * 1024);
  float4 v = src[threadIdx.x];
  b16* dst = Xg + (size_t)r * 1024 + threadIdx.x * 4;
  dst[0] = __float2bfloat16(v.x);
  dst[1] = __float2bfloat16(v.y);
  dst[2] = __float2bfloat16(v.z);
  dst[3] = __float2bfloat16(v.w);
}

// ---------------------------------------------------------------- stack two fp32 [rows_each x k] into bf16 [2*rows_each x k]
__global__ void cvt_cat2(const float* __restrict__ s0, const float* __restrict__ s1,
                         b16* __restrict__ out, int rows_each, int k, int total) {
  for (int idx = blockIdx.x * 256 + threadIdx.x; idx < total; idx += gridDim.x * 256) {
    int row = idx / k, col = idx - row * k;
    float v = (row < rows_each) ? s0[(size_t)row * k + col]
                                : s1[(size_t)(row - rows_each) * k + col];
    out[idx] = __float2bfloat16(v);
  }
}

// ---------------------------------------------------------------- bias0[j] = (bih+bhh) per cell, j in [0,4096)
__global__ void prep_bias(const float* bf1, const float* bf2, const float* bb1,
                          const float* bb2, float* out) {
  int j = blockIdx.x * 256 + threadIdx.x;
  int c = j >> 11, jj = j & 2047;
  out[j] = c ? (bb1[jj] + bb2[jj]) : (bf1[jj] + bf2[jj]);
}

// ---------------------------------------------------------------- pad dW [1074x2148] -> bf16 [1152x2176], db -> dbpad[1152]
__global__ void prep_dw(const float* __restrict__ dW, const float* __restrict__ db,
                        b16* __restrict__ dWpad, float* __restrict__ dbpad) {
  int idx = blockIdx.x * 256 + threadIdx.x;  // grid sized to exactly 1152*2176
  int r = idx / 2176, k = idx - r * 2176;
  float v = (r < 1074 && k < 2148) ? dW[(size_t)r * 2148 + k] : 0.0f;
  dWpad[idx] = __float2bfloat16(v);
  if (idx < 1152) dbpad[idx] = (idx < 1074) ? db[idx] : 0.0f;
}

// ---------------------------------------------------------------- bf16 GEMM: C[MxN] = A[MxK] @ B2[NxK]^T + bias (opt tanh)
// 128x128 tile, BK=64, global_load_lds(16B) staging with XOR chunk swizzle.
__global__ __launch_bounds__(256) void gemm_bt(
    const b16* __restrict__ A, const b16* __restrict__ B2, b16* __restrict__ C,
    const float* __restrict__ bias, int M, int N, int K, int act) {
  __shared__ __align__(16) b16 As[128 * 64];
  __shared__ __align__(16) b16 Bs[128 * 64];
  const int tid = threadIdx.x;
  const int w = tid >> 6, lane = tid & 63;
  const int quad = lane >> 4, lane16 = lane & 15;
  const int m0 = blockIdx.y * 128, n0 = blockIdx.x * 128;
  const int wm = (w >> 1) * 64, wn = (w & 1) * 64;
  float4v acc[4][4] = {};
  for (int kt = 0; kt < K; kt += 64) {
    __syncthreads();
    #pragma unroll
    for (int i = 0; i < 4; ++i) {
      int s = (i * 4 + w) * 64 + lane;
      int rr = s >> 3, ch = s & 7;
      int gch = ch ^ (rr & 7);
      load_lds16(A + (size_t)(m0 + rr) * K + kt + gch * 8, (char*)As + (i * 4 + w) * 1024);
      load_lds16(B2 + (size_t)(n0 + rr) * K + kt + gch * 8, (char*)Bs + (i * 4 + w) * 1024);
    }
    __syncthreads();
    #pragma unroll
    for (int ks = 0; ks < 2; ++ks) {
      short8 af[4], bfr[4];
      #pragma unroll
      for (int a = 0; a < 4; ++a) {
        int rr = wm + a * 16 + lane16;
        int gg = ks * 4 + quad;
        af[a] = *(const short8*)(As + rr * 64 + (gg ^ (rr & 7)) * 8);
      }
      #pragma unroll
      for (int b = 0; b < 4; ++b) {
        int rr = wn + b * 16 + lane16;
        int gg = ks * 4 + quad;
        bfr[b] = *(const short8*)(Bs + rr * 64 + (gg ^ (rr & 7)) * 8);
      }
      #pragma unroll
      for (int a = 0; a < 4; ++a)
        #pragma unroll
        for (int b = 0; b < 4; ++b)
          acc[a][b] = __builtin_amdgcn_mfma_f32_16x16x32_bf16(af[a], bfr[b], acc[a][b], 0, 0, 0);
    }
  }
  #pragma unroll
  for (int a = 0; a < 4; ++a) {
    #pragma unroll
    for (int b = 0; b < 4; ++b) {
      int col = n0 + wn + b * 16 + lane16;
      float bv = bias ? bias[col] : 0.0f;
      #pragma unroll
      for (int rg = 0; rg < 4; ++rg) {
        int row = m0 + wm + a * 16 + quad * 4 + rg;
        float v = acc[a][b][rg] + bv;
        if (act) v = tanhf(v);
        C[(size_t)row * N + col] = __float2bfloat16(v);
      }
    }
  }
}

// ---------------------------------------------------------------- persistent LSTM scan (one layer, 2 cells)
// 256 blocks x 512 thr. Block: cell c, hidden slice hs=p*32, batch slice rb=r*16.
// Gates for step t: Xproj[t] (precomputed, incl. biases) + h(t-1) @ Whh^T.
// h exchange through the COHERENT point (MALL) via sc0 sc1 loads/stores; flags
// are RELAXED agent atomics (no L2 cache maintenance on the critical path).
__global__ __launch_bounds__(512) void lstm_scan(
    const b16* __restrict__ Xproj,   // [128*128][4096]
    const b16* __restrict__ Whh,     // [2][2048][512] bf16
    b16* __restrict__ hseq,          // [128*128][1024]
    int* __restrict__ flags) {       // [128][16] counters, stride-16 ints
  __shared__ __align__(16) b16 As[16 * 528];
  __shared__ __align__(16) float gbuf[8][16][16];
  const int tid = threadIdx.x;
  const int bid = blockIdx.x;
  const int p = bid >> 4, d = bid & 15;   // domain d = c*8 + r
  const int c = d >> 3, r = d & 7;
  const int rb = r * 16, hs = p * 32;
  const int w = tid >> 6, lane = tid & 63;
  const int quad = lane >> 4, lane16 = lane & 15;
  const int gate = w >> 1, half = w & 1;
  const int colbase = gate * 512 + hs + half * 16;

  // resident weight fragments: wave w owns 16 gate-columns, all K=512
  short8 bfrag[16];
  {
    const b16* wp = Whh + ((size_t)(c * 2048 + colbase + lane16)) * 512 + quad * 8;
    #pragma unroll
    for (int ks = 0; ks < 16; ++ks) bfrag[ks] = *(const short8*)(wp + ks * 32);
  }
  // cell-update ownership: threads 0..255, batch row rb+bloc, hidden pair hs+2*hp
  const int bloc = tid >> 4, hp = tid & 15;
  float cs0 = 0.0f, cs1 = 0.0f;

  for (int t = 0; t < T_; ++t) {
    // prefetch Xproj gate dwords before the poll (plain cached loads)
    unsigned xpr[4];
    if (tid < 256) {
      const unsigned* xb =
          (const unsigned*)(Xproj + ((size_t)t * 128 + rb + bloc) * 4096 + c * 2048 + hs + hp * 2);
      #pragma unroll
      for (int g4 = 0; g4 < 4; ++g4) xpr[g4] = xb[g4 * 256];
    }
    float4v acc = {0.f, 0.f, 0.f, 0.f};
    if (t > 0) {
      if (tid == 0) {
        int* fp = flags + ((t - 1) * 16 + d) * 16;
        while (__hip_atomic_load(fp, __ATOMIC_RELAXED, __HIP_MEMORY_SCOPE_AGENT) < 16) {}
      }
      __syncthreads();
      {  // stage h(t-1)[rb..rb+16, cell c] -> LDS [16][528] via MALL (sc0 sc1)
        const int row = tid >> 5, chunk = tid & 31;
        const b16* g = hseq + ((size_t)(t - 1) * 128 + rb + row) * 1024 + c * 512 + chunk * 16;
        uint4 v0, v1;
        asm volatile("global_load_dwordx4 %0, %2, off sc0 sc1\n\t"
                     "global_load_dwordx4 %1, %2, off offset:16 sc0 sc1"
                     : "=&v"(v0), "=&v"(v1) : "v"(g) : "memory");
        asm volatile("s_waitcnt vmcnt(0)" ::: "memory");
        *(uint4*)(As + row * 528 + chunk * 16) = v0;
        *(uint4*)(As + row * 528 + chunk * 16 + 8) = v1;
      }
      __syncthreads();
      #pragma unroll
      for (int ks = 0; ks < 16; ++ks) {
        short8 af = *(const short8*)(As + lane16 * 528 + ks * 32 + quad * 8);
        acc = __builtin_amdgcn_mfma_f32_16x16x32_bf16(af, bfrag[ks], acc, 0, 0, 0);
      }
    }
    #pragma unroll
    for (int rg = 0; rg < 4; ++rg) gbuf[w][quad * 4 + rg][lane16] = acc[rg];
    __syncthreads();
    if (tid < 256) {  // cell update: 2 adjacent hidden units per thread
      const size_t xrow = (size_t)t * 128 + rb + bloc;
      const int hhalf = hp >> 3;          // (2*hp)>>4
      const int ci = 2 * (hp & 7);        // (2*hp)&15
      float g0[4], g1[4];
      #pragma unroll
      for (int g4 = 0; g4 < 4; ++g4) {
        float2 gv = *(const float2*)&gbuf[g4 * 2 + hhalf][bloc][ci];
        g0[g4] = gv.x + blo(xpr[g4]);
        g1[g4] = gv.y + bhi(xpr[g4]);
      }
      float i0 = sigm(g0[0]), f0 = sigm(g0[1]), gg0 = tanhf(g0[2]), o0 = sigm(g0[3]);
      float i1 = sigm(g1[0]), f1 = sigm(g1[1]), gg1 = tanhf(g1[2]), o1 = sigm(g1[3]);
      cs0 = f0 * cs0 + i0 * gg0;
      cs1 = f1 * cs1 + i1 * gg1;
      unsigned hv = pack2bf(o0 * tanhf(cs0), o1 * tanhf(cs1));
      unsigned* ha = (unsigned*)(hseq + xrow * 1024 + c * 512 + hs) + hp;
      asm volatile("global_store_dword %0, %1, off sc0 sc1" :: "v"(ha), "v"(hv) : "memory");
    }
    asm volatile("s_waitcnt vmcnt(0)" ::: "memory");
    __syncthreads();
    if (tid == 0)
      __hip_atomic_fetch_add(&flags[(t * 16 + d) * 16], 1, __ATOMIC_RELAXED,
                             __HIP_MEMORY_SCOPE_AGENT);
  }
}

// ---------------------------------------------------------------- build rep row [target | context | src_e | pad], write target fp32 out
__global__ void build_rep(const int* __restrict__ article, const int* __restrict__ positions,
                          const int* __restrict__ srcs, const float* __restrict__ E,
                          const float* __restrict__ src_emb, const b16* __restrict__ Xg,
                          const b16* __restrict__ h2seq, b16* __restrict__ rep,
                          float* __restrict__ out) {
  int b = blockIdx.x, tid = threadIdx.x;
  int pos = positions[b], sc = srcs[b];
  for (int k = tid; k < 2176; k += 256) {
    b16 v;
    if (k < 1024)      v = Xg[((size_t)pos * 128 + b) * 1024 + k];
    else if (k < 2048) v = h2seq[((size_t)127 * 128 + b) * 1024 + (k - 1024)];
    else if (k < 2148) v = __float2bfloat16(src_emb[sc * 100 + (k - 2048)]);
    else               v = __float2bfloat16(0.0f);
    rep[(size_t)b * 2176 + k] = v;
  }
  int tok = article[b * T_ + pos];
  for (int k = tid; k < 1024; k += 256)
    out[512 + b * 1024 + k] = E[(size_t)tok * 1024 + k];
}

// ---------------------------------------------------------------- logits + probs
__global__ void classifier(const b16* __restrict__ feat, const float* __restrict__ cW,
                           const float* __restrict__ cb, float* __restrict__ out) {
  __shared__ float red[256];
  int tid = threadIdx.x;
  int pairIdx = tid >> 3, jc = tid & 7;
  int bl = pairIdx >> 1, l = pairIdx & 1;
  int b = blockIdx.x * 16 + bl;
  int j0 = jc * 135, j1 = (j0 + 135 < 1074) ? j0 + 135 : 1074;
  float s = 0.f;
  for (int j = j0; j < j1; ++j)
    s += __bfloat162float(feat[(size_t)b * 1152 + j]) * cW[l * 1074 + j];
  red[tid] = s;
  __syncthreads();
  if (jc == 0) {
    float tot = 0.f;
    #pragma unroll
    for (int q = 0; q < 8; ++q) tot += red[pairIdx * 8 + q];
    tot += cb[l];
    out[b * 2 + l] = tot;
    out[256 + b * 2 + l] = 1.0f / (1.0f + __expf(-tot));
  }
}

// ----------------------------------------------------------------
extern "C" void kernel_launch(void* const* d_in, const int* in_sizes, int n_in,
                              void* d_out, int out_size, void* d_ws, size_t ws_size,
                              hipStream_t stream) {
  const int* article = (const int*)d_in[0];
  const int* positions = (const int*)d_in[1];
  const int* srcs = (const int*)d_in[2];
  const float* E = (const float*)d_in[3];
  const float* src_emb = (const float*)d_in[4];
  const float* Wih0f = (const float*)d_in[5];
  const float* Whh0f = (const float*)d_in[6];
  const float* bih0f = (const float*)d_in[7];
  const float* bhh0f = (const float*)d_in[8];
  const float* Wih0b = (const float*)d_in[9];
  const float* Whh0b = (const float*)d_in[10];
  const float* bih0b = (const float*)d_in[11];
  const float* bhh0b = (const float*)d_in[12];
  const float* Wih1f = (const float*)d_in[13];
  const float* Whh1f = (const float*)d_in[14];
  const float* bih1f = (const float*)d_in[15];
  const float* bhh1f = (const float*)d_in[16];
  const float* Wih1b = (const float*)d_in[17];
  const float* Whh1b = (const float*)d_in[18];
  const float* bih1b = (const float*)d_in[19];
  const float* bhh1b = (const float*)d_in[20];
  const float* dW = (const float*)d_in[21];
  const float* db = (const float*)d_in[22];
  const float* cW = (const float*)d_in[23];
  const float* cb = (const float*)d_in[24];

  char* ws = (char*)d_ws;
  size_t off = 0;
  auto carve = [&](size_t bytes) -> void* {
    void* p = ws + off;
    off += (bytes + 255) & ~(size_t)255;
    return p;
  };
  b16* Xg    = (b16*)carve((size_t)16384 * 1024 * 2);
  b16* h1seq = (b16*)carve((size_t)16384 * 1024 * 2);
  b16* h2seq = (b16*)carve((size_t)16384 * 1024 * 2);
  b16* Xproj = (b16*)carve((size_t)16384 * 4096 * 2);  // reused for layer0 and layer1
  b16* W0cat = (b16*)carve((size_t)4096 * 1024 * 2);
  b16* W1cat = (b16*)carve((size_t)4096 * 1024 * 2);
  b16* Whh0  = (b16*)carve((size_t)2 * 2048 * 512 * 2);
  b16* Whh1  = (b16*)carve((size_t)2 * 2048 * 512 * 2);
  b16* dWpad = (b16*)carve((size_t)1152 * 2176 * 2);
  b16* rep   = (b16*)carve((size_t)128 * 2176 * 2);
  b16* feat  = (b16*)carve((size_t)128 * 1152 * 2);
  float* bias0 = (float*)carve(4096 * 4);
  float* bias1 = (float*)carve(4096 * 4);
  float* dbpad = (float*)carve(1152 * 4);
  int* flags1 = (int*)carve(128 * 16 * 16 * 4);
  int* flags2 = (int*)carve(128 * 16 * 16 * 4);
  (void)ws_size; (void)in_sizes; (void)n_in; (void)out_size;

  hipMemsetAsync(flags1, 0, 2 * 128 * 16 * 16 * 4, stream);

  gather_x<<<16384, 256, 0, stream>>>(article, E, Xg);
  cvt_cat2<<<8192, 256, 0, stream>>>(Wih0f, Wih0b, W0cat, 2048, 1024, 4096 * 1024);
  cvt_cat2<<<8192, 256, 0, stream>>>(Wih1f, Wih1b, W1cat, 2048, 1024, 4096 * 1024);
  cvt_cat2<<<8192, 256, 0, stream>>>(Whh0f, Whh0b, Whh0, 2048, 512, 4096 * 512);
  cvt_cat2<<<8192, 256, 0, stream>>>(Whh1f, Whh1b, Whh1, 2048, 512, 4096 * 512);
  prep_bias<<<16, 256, 0, stream>>>(bih0f, bhh0f, bih0b, bhh0b, bias0);
  prep_bias<<<16, 256, 0, stream>>>(bih1f, bhh1f, bih1b, bhh1b, bias1);
  prep_dw<<<9792, 256, 0, stream>>>(dW, db, dWpad, dbpad);

  gemm_bt<<<dim3(32, 128), 256, 0, stream>>>(Xg, W0cat, Xproj, bias0, 16384, 4096, 1024, 0);
  lstm_scan<<<256, 512, 0, stream>>>(Xproj, Whh0, h1seq, flags1);
  gemm_bt<<<dim3(32, 128), 256, 0, stream>>>(h1seq, W1cat, Xproj, bias1, 16384, 4096, 1024, 0);
  lstm_scan<<<256, 512, 0, stream>>>(Xproj, Whh1, h2seq, flags2);

  build_rep<<<128, 256, 0, stream>>>(article, positions, srcs, E, src_emb, Xg, h2seq, rep,
                                     (float*)d_out);
  gemm_bt<<<dim3(9, 1), 256, 0, stream>>>(rep, dWpad, feat, dbpad, 128, 1152, 2176, 1);
  classifier<<<8, 256, 0, stream>>>(feat, cW, cb, (float*)d_out);
}